// Round 4
// baseline (662.956 us; speedup 1.0000x reference)
//
#include <hip/hip_runtime.h>

// QLORA: Y = X @ (W_nf4*c1*c2) + (X @ L1) @ L2
// M=8192, K=4096, N=4096, RANK=16.
// R7 changes vs R5 (R4/R6 counted-vmcnt 8-phase failed twice -> abandoned;
// back to the verified 2-barrier structure):
//  - GEMM: BK 32 -> 64 via two staged buffer pairs (As/Bs[2]) per iteration:
//    half the barrier-drain stalls, identical verified swizzle/frag/epilogue
//    code per buffer. 1D grid with bijective XCD swizzle (2048 % 8 == 0).
//  - wprep: LDS-transpose version. Old store was 16B/lane @ 8KB stride
//    (scatter, ~4x write amplification); now tile staged [n][k] bf16 in LDS
//    (pad 8 for 16B alignment), stores go out as 128B contiguous bursts.
//  - xl1: 4-wave K-split per block + LDS reduce (R5 ran 1 wave/block = 2
//    waves/CU, latency-bound).

#define M_ROWS 8192
#define K_DIM  4096
#define N_OUT  4096
#define CVT_BLOCKS 16384        // M*K/8/256
#define WP_BLOCKS  4096         // (N/64)*(K/64)

typedef float  f32x16 __attribute__((ext_vector_type(16)));
typedef float  f32x4  __attribute__((ext_vector_type(4)));
typedef __bf16 bf16x8 __attribute__((ext_vector_type(8)));
typedef unsigned short ushort8v __attribute__((ext_vector_type(8)));

__device__ float          Tg[(size_t)M_ROWS * 16];   // T = X@L1, fp32
__device__ unsigned short L1t[16 * K_DIM];           // L1^T, bf16
__device__ unsigned short L2t[N_OUT * 16];           // L2^T, bf16

__device__ __forceinline__ unsigned short f2bf(float f) {
    __bf16 h = (__bf16)f;                       // native v_cvt (RNE)
    union { __bf16 h; unsigned short u; } v; v.h = h;
    return v.u;
}

// ---------------------------------------------------------- X fp32 -> bf16
__global__ __launch_bounds__(256) void cvt_kernel(
        const float* __restrict__ X, ushort8v* __restrict__ Xh) {
    size_t tid = (size_t)blockIdx.x * 256 + threadIdx.x;
    const float4* xp = (const float4*)X;
    float4 a = xp[tid * 2];
    float4 b = xp[tid * 2 + 1];
    ushort8v o;
    o[0] = f2bf(a.x); o[1] = f2bf(a.y); o[2] = f2bf(a.z); o[3] = f2bf(a.w);
    o[4] = f2bf(b.x); o[5] = f2bf(b.y); o[6] = f2bf(b.z); o[7] = f2bf(b.w);
    Xh[tid] = o;
}

// -------------------- W' = W_nf4*c1*c2, transposed store via LDS 64x64 tile
// Phase A: coalesced row reads, dequant to bf16, scatter into LDS [n][k].
// Phase B: ds_read_b128 per (n, k8), store 16B; lanes 0..7 cover one n-row's
// 64 k = 128B contiguous global bursts.
__global__ __launch_bounds__(256) void wprep_kernel(
        const float* __restrict__ Wnf4, const float* __restrict__ c1p,
        const float* __restrict__ c2,   unsigned short* __restrict__ Wt) {
    __shared__ unsigned short tile[64][72];   // [n][k], pad 8 keeps 16B align
    const int t  = threadIdx.x;
    const int wb = blockIdx.x;
    const int n0 = (wb & 63) * 64;
    const int k0 = (wb >> 6) * 64;
    const float c1 = *c1p;

    #pragma unroll
    for (int i = 0; i < 4; ++i) {
        int idx = i * 1024 + t * 4;
        int k = idx >> 6, n4 = idx & 63;
        size_t g = (size_t)(k0 + k) * N_OUT + n0 + n4;
        float4 w = *(const float4*)&Wnf4[g];
        float4 s = *(const float4*)&c2[g];
        tile[n4    ][k] = f2bf(w.x * c1 * s.x);
        tile[n4 + 1][k] = f2bf(w.y * c1 * s.y);
        tile[n4 + 2][k] = f2bf(w.z * c1 * s.z);
        tile[n4 + 3][k] = f2bf(w.w * c1 * s.w);
    }
    __syncthreads();

    #pragma unroll
    for (int i = 0; i < 2; ++i) {
        int task = i * 256 + t;
        int n = task >> 3, k8 = (task & 7) * 8;
        ushort8v o = *(const ushort8v*)&tile[n][k8];
        *(ushort8v*)&Wt[(size_t)(n0 + n) * K_DIM + k0 + k8] = o;
    }
}

// ------------------- tiny transposes: L1 -> L1t (bf16), L2 -> L2t (bf16)
__global__ __launch_bounds__(256) void lorap_kernel(
        const float* __restrict__ L1, const float* __restrict__ L2) {
    const int idx = blockIdx.x * 256 + threadIdx.x;
    if (idx < K_DIM) {                       // L1t, thread = one k
        const float4* lp = (const float4*)&L1[(size_t)idx * 16];
        float4 r0 = lp[0], r1 = lp[1], r2 = lp[2], r3 = lp[3];
        float v[16] = {r0.x, r0.y, r0.z, r0.w, r1.x, r1.y, r1.z, r1.w,
                       r2.x, r2.y, r2.z, r2.w, r3.x, r3.y, r3.z, r3.w};
        #pragma unroll
        for (int r = 0; r < 16; ++r)
            L1t[(size_t)r * K_DIM + idx] = f2bf(v[r]);
    } else {                                 // L2t, thread = one n
        const int n = idx - K_DIM;
        ushort8v a, b;
        #pragma unroll
        for (int r = 0; r < 8; ++r) a[r] = f2bf(L2[(size_t)r * N_OUT + n]);
        #pragma unroll
        for (int r = 0; r < 8; ++r) b[r] = f2bf(L2[(size_t)(r + 8) * N_OUT + n]);
        *(ushort8v*)&L2t[(size_t)n * 16]     = a;
        *(ushort8v*)&L2t[(size_t)n * 16 + 8] = b;
    }
}

// ------------------------------------------------- T = Xh @ L1  (8192 x 16)
// 512 blocks x 256 thr; wave wv handles K-chunk [wv*1024, +1024), LDS-reduce.
__global__ __launch_bounds__(256) void xl1_kernel(const __bf16* __restrict__ Xh) {
    __shared__ float red[4][256];
    const int m0 = blockIdx.x * 16;
    const int t = threadIdx.x, wv = t >> 6, lane = t & 63;
    const int l15 = lane & 15, l4 = lane >> 4;
    const __bf16* ap = Xh + (size_t)(m0 + l15) * K_DIM + wv * 1024 + l4 * 8;
    const __bf16* bp = (const __bf16*)L1t + (size_t)l15 * K_DIM + wv * 1024 + l4 * 8;
    f32x4 acc = {};
    #pragma unroll 8
    for (int k = 0; k < 1024; k += 32) {
        bf16x8 a = *(const bf16x8*)(ap + k);
        bf16x8 b = *(const bf16x8*)(bp + k);
        acc = __builtin_amdgcn_mfma_f32_16x16x32_bf16(a, b, acc, 0, 0, 0);
    }
    #pragma unroll
    for (int r = 0; r < 4; ++r) red[wv][(l4 * 4 + r) * 16 + l15] = acc[r];
    __syncthreads();
    if (wv == 0) {
        #pragma unroll
        for (int r = 0; r < 4; ++r) {
            int e = (l4 * 4 + r) * 16 + l15;
            Tg[(size_t)(m0 + l4 * 4 + r) * 16 + l15] =
                red[0][e] + red[1][e] + red[2][e] + red[3][e];
        }
    }
}

// ----------------------------------------------------------------- bf16 GEMM
// C[M][N] = A[M][K]*Bt[N][K]^T + T@L2t^T ; 128x128 tile, BK=64 (2x 32-wide
// staged buffers), 4 waves. Wave w: 64x64 subtile as 2x2 grid of 32x32x16
// MFMAs. Verified R5 swizzle: LDS row-major [row][32k], 4x16B slots/row,
// phys slot = logical ^ ((row>>1)&3), staged via pre-swizzled global source.
#define COMPUTE(B) do { \
    bf16x8 af[2][2], bf[2][2]; \
    _Pragma("unroll") for (int mt = 0; mt < 2; ++mt) \
      _Pragma("unroll") for (int ks = 0; ks < 2; ++ks) { \
        int row = wm + mt * 32 + l32; \
        int slot = (2 * ks + half) ^ rsw; \
        af[mt][ks] = *(const bf16x8*)(&As[B][0] + row * 32 + slot * 8); \
      } \
    _Pragma("unroll") for (int nt = 0; nt < 2; ++nt) \
      _Pragma("unroll") for (int ks = 0; ks < 2; ++ks) { \
        int row = wn + nt * 32 + l32; \
        int slot = (2 * ks + half) ^ rsw; \
        bf[nt][ks] = *(const bf16x8*)(&Bs[B][0] + row * 32 + slot * 8); \
      } \
    _Pragma("unroll") for (int ks = 0; ks < 2; ++ks) \
      _Pragma("unroll") for (int mt = 0; mt < 2; ++mt) \
        _Pragma("unroll") for (int nt = 0; nt < 2; ++nt) \
          acc[mt][nt] = __builtin_amdgcn_mfma_f32_32x32x16_bf16( \
              af[mt][ks], bf[nt][ks], acc[mt][nt], 0, 0, 0); \
} while (0)

__global__ __launch_bounds__(256) void gemm_bt_kernel(
        const __bf16* __restrict__ A, const __bf16* __restrict__ Bt,
        float* __restrict__ C) {
    __shared__ __bf16 As[2][128 * 32];   // 16 KB
    __shared__ __bf16 Bs[2][128 * 32];   // 16 KB

    const int t    = threadIdx.x;
    const int w    = t >> 6;
    const int lane = t & 63;
    const int half = lane >> 5;       // 0..1
    const int l32  = lane & 31;

    // bijective XCD swizzle: 2048 blocks, 2048 % 8 == 0
    const int bid = blockIdx.x;
    const int swz = (bid & 7) * 256 + (bid >> 3);
    const int m0  = (swz >> 5) * 128;
    const int n0  = (swz & 31) * 128;

    const int wm   = (w >> 1) * 64;
    const int wn   = (w & 1) * 64;

    // staging source permutation: lane l -> row l>>2,
    // phys slot l&3 holds logical slot (l&3)^((l>>3)&3)
    const int srow = lane >> 2;
    const int scol = ((lane & 3) ^ ((lane >> 3) & 3)) * 8;
    // read-side swizzle: (row>>1)&3 with row = base32 + l32
    const int rsw = (l32 >> 1) & 3;

    f32x16 acc[2][2] = {};

    for (int kb = 0; kb < K_DIM; kb += 64) {
        __syncthreads();
        #pragma unroll
        for (int b = 0; b < 2; ++b) {
            #pragma unroll
            for (int j = 0; j < 2; ++j) {
                int row = w * 32 + j * 16 + srow;
                const __bf16* gp = A + (size_t)(m0 + row) * K_DIM + kb + b * 32 + scol;
                __builtin_amdgcn_global_load_lds(
                    (const __attribute__((address_space(1))) unsigned int*)gp,
                    (__attribute__((address_space(3))) unsigned int*)
                        (&As[b][0] + (w * 32 + j * 16) * 32),
                    16, 0, 0);
            }
            #pragma unroll
            for (int j = 0; j < 2; ++j) {
                int row = w * 32 + j * 16 + srow;
                const __bf16* gp = Bt + (size_t)(n0 + row) * K_DIM + kb + b * 32 + scol;
                __builtin_amdgcn_global_load_lds(
                    (const __attribute__((address_space(1))) unsigned int*)gp,
                    (__attribute__((address_space(3))) unsigned int*)
                        (&Bs[b][0] + (w * 32 + j * 16) * 32),
                    16, 0, 0);
            }
        }
        __syncthreads();

        COMPUTE(0);
        COMPUTE(1);
    }

    // ---- LoRA epilogue (verified in R5): acc += T(128x16) @ L2t^T, K=16.
    // 32x32x16 A-frag: lane row = l32, k = half*8 + j  -> T[row][half*8..+8]
    // 32x32x16 B-frag: lane col = l32, k = half*8 + j  -> L2t[col][half*8..+8]
    {
        bf16x8 afl[2], bfl[2];
        #pragma unroll
        for (int mt = 0; mt < 2; ++mt) {
            const float* tp = Tg + (size_t)(m0 + wm + mt * 32 + l32) * 16 + half * 8;
            float4 p0 = *(const float4*)tp;
            float4 p1 = *(const float4*)(tp + 4);
            afl[mt][0] = (__bf16)p0.x; afl[mt][1] = (__bf16)p0.y;
            afl[mt][2] = (__bf16)p0.z; afl[mt][3] = (__bf16)p0.w;
            afl[mt][4] = (__bf16)p1.x; afl[mt][5] = (__bf16)p1.y;
            afl[mt][6] = (__bf16)p1.z; afl[mt][7] = (__bf16)p1.w;
        }
        #pragma unroll
        for (int nt = 0; nt < 2; ++nt)
            bfl[nt] = *(const bf16x8*)((const __bf16*)L2t +
                        (size_t)(n0 + wn + nt * 32 + l32) * 16 + half * 8);
        #pragma unroll
        for (int mt = 0; mt < 2; ++mt)
            #pragma unroll
            for (int nt = 0; nt < 2; ++nt)
                acc[mt][nt] = __builtin_amdgcn_mfma_f32_32x32x16_bf16(
                    afl[mt], bfl[nt], acc[mt][nt], 0, 0, 0);
    }

    // epilogue: C/D 32x32 layout col=lane&31, row=(reg&3)+8*(reg>>2)+4*half
    #pragma unroll
    for (int mt = 0; mt < 2; ++mt)
        #pragma unroll
        for (int nt = 0; nt < 2; ++nt) {
            int col = n0 + wn + nt * 32 + l32;
            #pragma unroll
            for (int reg = 0; reg < 16; ++reg) {
                int row = m0 + wm + mt * 32 + (reg & 3) + 8 * (reg >> 2) + 4 * half;
                C[(size_t)row * N_OUT + col] = acc[mt][nt][reg];
            }
        }
}

extern "C" void kernel_launch(void* const* d_in, const int* in_sizes, int n_in,
                              void* d_out, int out_size, void* d_ws, size_t ws_size,
                              hipStream_t stream) {
    const float* X    = (const float*)d_in[0];
    const float* Wnf4 = (const float*)d_in[1];
    const float* c1   = (const float*)d_in[2];   // scalar
    const float* c2   = (const float*)d_in[3];
    const float* L1   = (const float*)d_in[4];
    const float* L2   = (const float*)d_in[5];
    float* Y = (float*)d_out;

    unsigned short* Xh = (unsigned short*)d_ws;                                       // 64 MB
    unsigned short* Wt = (unsigned short*)((char*)d_ws + (size_t)M_ROWS * K_DIM * 2); // 32 MB

    cvt_kernel<<<CVT_BLOCKS, 256, 0, stream>>>(X, (ushort8v*)Xh);
    wprep_kernel<<<WP_BLOCKS, 256, 0, stream>>>(Wnf4, c1, c2, Wt);
    lorap_kernel<<<32, 256, 0, stream>>>(L1, L2);
    xl1_kernel<<<M_ROWS / 16, 256, 0, stream>>>((const __bf16*)Xh);
    gemm_bt_kernel<<<(M_ROWS / 128) * (N_OUT / 128), 256, 0, stream>>>(
        (const __bf16*)Xh, (const __bf16*)Wt, Y);
}